// Round 7
// baseline (156.886 us; speedup 1.0000x reference)
//
#include <hip/hip_runtime.h>

// Conv1dFFT via polyphase: y[b] = IFFT_8192( sum_p G_p * FFT_8192(x_polyphase_p) )
// 3-kernel split for occupancy:
//  k1: 512 blocks (row,half) x 1024thr -> 2 fwd FFTs + P/Q partial acc (2 blk/CU)
//  k2: 512 blocks (row,q)   x 512thr  -> sum partials + inverse C0..C9 on 4096-half
//  k3: streaming final h=4096 DIT stage in place
// Fallback single kernel if ws too small.

#define TK      8192
#define LOG2TK  13
#define HALF_TK 4096
#define KFOLD   8
#define NPAIR   4
#define TFULL   65536
#define RSQ2    0.70710678118654752440f

#define SW(i) ((i) ^ (((i) >> 4) & 15))

#define WAVE_SYNC() do { asm volatile("" ::: "memory"); __builtin_amdgcn_wave_barrier(); } while (0)

__device__ __forceinline__ float2 cmul(float2 a, float2 b) {
    return make_float2(a.x * b.x - a.y * b.y, a.x * b.y + a.y * b.x);
}
__device__ __forceinline__ unsigned br13(unsigned r) { return __brev(r) >> 19u; }

__device__ float2 g_W[HALF_TK];        // e^{-2pi i t/8192}
__device__ float2 g_P[NPAIR * TK];     // bit-reversed order
__device__ float2 g_Q[NPAIR * TK];     // bit-reversed order

__global__ void build_twiddle_kernel() {
    int t = blockIdx.x * blockDim.x + threadIdx.x;
    if (t < HALF_TK) {
        double ang = -2.0 * 3.14159265358979323846 * (double)t / (double)TK;
        g_W[t] = make_float2((float)cos(ang), (float)sin(ang));
    }
}

__global__ void build_pq_kernel(const float* __restrict__ filt) {
    int t = blockIdx.x * blockDim.x + threadIdx.x;
    if (t >= TK) return;
    float fm[KFOLD];
#pragma unroll
    for (int m = 0; m < KFOLD; ++m) fm[m] = filt[m * TK + t];
    float2 G[KFOLD];
#pragma unroll
    for (int p = 0; p < KFOLD; ++p) {
        double sr = 0.0, si = 0.0;
#pragma unroll
        for (int m = 0; m < KFOLD; ++m) {
            double ang = -2.0 * 3.14159265358979323846 * (double)((p * m) & 7) / 8.0;
            sr += (double)fm[m] * cos(ang);
            si += (double)fm[m] * sin(ang);
        }
        double ang2 = -2.0 * 3.14159265358979323846 * (double)(p * t) / (double)TFULL;
        double c2 = cos(ang2), s2 = sin(ang2);
        G[p] = make_float2((float)((sr * c2 - si * s2) * 0.125),
                           (float)((sr * s2 + si * c2) * 0.125));
    }
    const float norm = 0.5f / (float)TK;
    unsigned r = br13((unsigned)t);
#pragma unroll
    for (int j = 0; j < NPAIR; ++j) {
        float2 g0 = G[2 * j], g1 = G[2 * j + 1];
        g_P[j * TK + r] = make_float2((g0.x + g1.y) * norm, (g0.y - g1.x) * norm);
        g_Q[j * TK + r] = make_float2((g0.x - g1.y) * norm, (g0.y + g1.x) * norm);
    }
}

// Forward DIF radix-8 pass: stages (4s, 2s, s), s = 1<<C. 1024 threads, 8192 pts.
template<int C>
__device__ __forceinline__ void fwd_pass(float2* buf, int tid) {
    const int s = 1 << C;
    const int q0 = tid & (s - 1);
    const int i0 = ((tid >> C) << (C + 3)) + q0;
    float2 e[8];
#pragma unroll
    for (int t = 0; t < 8; ++t) e[t] = buf[SW(i0 + t * s)];
    float2 w1, w2, w3;
    if (C == 0) { w1 = make_float2(1.f, 0.f); w2 = w1; w3 = w1; }
    else { w1 = g_W[q0 << (10 - C)]; w2 = cmul(w1, w1); w3 = cmul(w2, w2); }
#pragma unroll
    for (int t = 0; t < 4; ++t) {
        float2 a = e[t], b = e[t + 4];
        float2 d = make_float2(a.x - b.x, a.y - b.y);
        e[t] = make_float2(a.x + b.x, a.y + b.y);
        d = cmul(d, w1);
        if (t == 1)      d = make_float2(RSQ2 * (d.x + d.y), RSQ2 * (d.y - d.x));
        else if (t == 2) d = make_float2(d.y, -d.x);
        else if (t == 3) d = make_float2(RSQ2 * (d.y - d.x), -RSQ2 * (d.x + d.y));
        e[t + 4] = d;
    }
#pragma unroll
    for (int t0 = 0; t0 < 8; t0 += 4) {
#pragma unroll
        for (int t = 0; t < 2; ++t) {
            int i = t0 + t;
            float2 a = e[i], b = e[i + 2];
            float2 d = make_float2(a.x - b.x, a.y - b.y);
            e[i] = make_float2(a.x + b.x, a.y + b.y);
            d = cmul(d, w2);
            if (t == 1) d = make_float2(d.y, -d.x);
            e[i + 2] = d;
        }
    }
#pragma unroll
    for (int t = 0; t < 8; t += 2) {
        float2 a = e[t], b = e[t + 1];
        float2 d = make_float2(a.x - b.x, a.y - b.y);
        e[t] = make_float2(a.x + b.x, a.y + b.y);
        e[t + 1] = cmul(d, w3);
    }
#pragma unroll
    for (int t = 0; t < 8; ++t) buf[SW(i0 + t * s)] = e[t];
}

// Inverse DIT radix-8 pass: stages (s, 2s, 4s), conjugated twiddles.
// Works for any thread count covering the buffer (8 pts/thread).
template<int C>
__device__ __forceinline__ void inv_pass(float2* buf, int tid) {
    const int s = 1 << C;
    const int q0 = tid & (s - 1);
    const int i0 = ((tid >> C) << (C + 3)) + q0;
    float2 e[8];
#pragma unroll
    for (int t = 0; t < 8; ++t) e[t] = buf[SW(i0 + t * s)];
    float2 v1, v2, v3;
    if (C == 0) { v1 = make_float2(1.f, 0.f); v2 = v1; v3 = v1; }
    else { v1 = g_W[q0 << (10 - C)]; v1.y = -v1.y; v2 = cmul(v1, v1); v3 = cmul(v2, v2); }
#pragma unroll
    for (int t = 0; t < 8; t += 2) {
        float2 b = cmul(e[t + 1], v3);
        float2 a = e[t];
        e[t]     = make_float2(a.x + b.x, a.y + b.y);
        e[t + 1] = make_float2(a.x - b.x, a.y - b.y);
    }
#pragma unroll
    for (int t0 = 0; t0 < 8; t0 += 4) {
#pragma unroll
        for (int t = 0; t < 2; ++t) {
            int i = t0 + t;
            float2 b = cmul(e[i + 2], v2);
            if (t == 1) b = make_float2(-b.y, b.x);
            float2 a = e[i];
            e[i]     = make_float2(a.x + b.x, a.y + b.y);
            e[i + 2] = make_float2(a.x - b.x, a.y - b.y);
        }
    }
#pragma unroll
    for (int t = 0; t < 4; ++t) {
        float2 b = cmul(e[t + 4], v1);
        if (t == 1)      b = make_float2(RSQ2 * (b.x - b.y), RSQ2 * (b.x + b.y));
        else if (t == 2) b = make_float2(-b.y, b.x);
        else if (t == 3) b = make_float2(-RSQ2 * (b.x + b.y), RSQ2 * (b.x - b.y));
        float2 a = e[t];
        e[t]     = make_float2(a.x + b.x, a.y + b.y);
        e[t + 4] = make_float2(a.x - b.x, a.y - b.y);
    }
#pragma unroll
    for (int t = 0; t < 8; ++t) buf[SW(i0 + t * s)] = e[t];
}

// Register radix-8 inverse C=0 pass (unit group twiddle): acc[8] -> e[8]
__device__ __forceinline__ void reg_inv_c0(const float2* acc, float2* e) {
#pragma unroll
    for (int t = 0; t < 8; t += 2) {
        float2 a = acc[t], bb = acc[t + 1];
        e[t]     = make_float2(a.x + bb.x, a.y + bb.y);
        e[t + 1] = make_float2(a.x - bb.x, a.y - bb.y);
    }
#pragma unroll
    for (int t0 = 0; t0 < 8; t0 += 4) {
        {
            float2 a = e[t0], bb = e[t0 + 2];
            e[t0]     = make_float2(a.x + bb.x, a.y + bb.y);
            e[t0 + 2] = make_float2(a.x - bb.x, a.y - bb.y);
        }
        {
            float2 a = e[t0 + 1], bb = e[t0 + 3];
            bb = make_float2(-bb.y, bb.x);
            e[t0 + 1] = make_float2(a.x + bb.x, a.y + bb.y);
            e[t0 + 3] = make_float2(a.x - bb.x, a.y - bb.y);
        }
    }
#pragma unroll
    for (int t = 0; t < 4; ++t) {
        float2 bb = e[t + 4];
        if (t == 1)      bb = make_float2(RSQ2 * (bb.x - bb.y), RSQ2 * (bb.x + bb.y));
        else if (t == 2) bb = make_float2(-bb.y, bb.x);
        else if (t == 3) bb = make_float2(-RSQ2 * (bb.x + bb.y), RSQ2 * (bb.x - bb.y));
        float2 a = e[t];
        e[t]     = make_float2(a.x + bb.x, a.y + bb.y);
        e[t + 4] = make_float2(a.x - bb.x, a.y - bb.y);
    }
}

__device__ __forceinline__ void stage1_store(float2* buf, int u, float2 a, float2 b2) {
    float2 w = g_W[u];
    buf[SW(u)] = make_float2(a.x + b2.x, a.y + b2.y);
    buf[SW(u + HALF_TK)] = cmul(make_float2(a.x - b2.x, a.y - b2.y), w);
}

// ---------------- k1: forward FFTs for one (row, half) ----------------
__global__ __launch_bounds__(1024, 8)
void fwd_half_kernel(const float* __restrict__ x,
                     float2* __restrict__ ph0, float2* __restrict__ ph1) {
    __shared__ float2 buf[TK];   // 64 KB -> 2 blocks/CU
    const int tid = threadIdx.x;
    const int r = blockIdx.x >> 1;
    const int h = blockIdx.x & 1;
    const float4* __restrict__ xrow4 =
        reinterpret_cast<const float4*>(x + (size_t)r * TFULL);

    float2 acc[8];
#pragma unroll
    for (int c = 0; c < 8; ++c) acc[c] = make_float2(0.f, 0.f);

    for (int jj = 0; jj < 2; ++jj) {          // j = 2h + jj
        // load + first DIF stage (h=4096). Same float4s both jj -> 2nd is L1-hit.
#pragma unroll
        for (int c4 = 0; c4 < 4; ++c4) {
            int u = c4 * 1024 + tid;
            float4 A = xrow4[2 * u + h];
            float4 B = xrow4[2 * (u + HALF_TK) + h];
            float2 a  = jj ? make_float2(A.z, A.w) : make_float2(A.x, A.y);
            float2 b2 = jj ? make_float2(B.z, B.w) : make_float2(B.x, B.y);
            stage1_store(buf, u, a, b2);
        }
        __syncthreads();
        fwd_pass<9>(buf, tid);
        __syncthreads();
        fwd_pass<6>(buf, tid);
        WAVE_SYNC();
        fwd_pass<3>(buf, tid);
        WAVE_SYNC();
        fwd_pass<0>(buf, tid);
        __syncthreads();
        const int j = 2 * h + jj;
        const float2* __restrict__ P = g_P + (size_t)j * TK;
        const float2* __restrict__ Q = g_Q + (size_t)j * TK;
#pragma unroll
        for (int c = 0; c < 8; ++c) {
            int rr = 8 * tid + c;
            unsigned t = br13((unsigned)rr);
            unsigned tm = (TK - t) & (TK - 1);
            int r2 = (int)br13(tm);
            float2 Zt = buf[SW(rr)];
            float2 Zm = buf[SW(r2)];
            float2 Pv = P[rr], Qv = Q[rr];
            acc[c].x += Zt.x * Pv.x - Zt.y * Pv.y + Zm.x * Qv.x + Zm.y * Qv.y;
            acc[c].y += Zt.x * Pv.y + Zt.y * Pv.x + Zm.x * Qv.y - Zm.y * Qv.x;
        }
        __syncthreads();
    }
    float2* __restrict__ dst = (h ? ph1 : ph0) + (size_t)r * TK;
#pragma unroll
    for (int c = 0; c < 8; ++c) dst[8 * tid + c] = acc[c];
}

// ------- k2: sum partials + inverse C0,C3,C6,C9 on one 4096-half -------
__global__ __launch_bounds__(512, 4)
void inv_half_kernel(float2* __restrict__ ph0, const float2* __restrict__ ph1) {
    __shared__ float2 sbuf[HALF_TK];   // 32 KB
    const int tid = threadIdx.x;
    const int r = blockIdx.x >> 1;
    const int q = blockIdx.x & 1;
    float2* __restrict__ b0 = ph0 + (size_t)r * TK + q * HALF_TK;
    const float2* __restrict__ b1 = ph1 + (size_t)r * TK + q * HALF_TK;

    float2 acc[8];
#pragma unroll
    for (int c = 0; c < 8; ++c) {
        int l = 8 * tid + c;
        float2 a0 = b0[l], a1 = b1[l];
        acc[c] = make_float2(a0.x + a1.x, a0.y + a1.y);
    }
    float2 e[8];
    reg_inv_c0(acc, e);
#pragma unroll
    for (int t = 0; t < 8; ++t) sbuf[SW(8 * tid + t)] = e[t];
    WAVE_SYNC();
    inv_pass<3>(sbuf, tid);   // half-local; twiddles depend only on i mod h
    WAVE_SYNC();
    inv_pass<6>(sbuf, tid);
    __syncthreads();
    // C9 (stages 512,1024,2048) computed in regs, stored straight to global
    {
        float2 v1 = g_W[tid << 1]; v1.y = -v1.y;
        float2 v2 = cmul(v1, v1), v3 = cmul(v2, v2);
        float2 f[8];
#pragma unroll
        for (int t = 0; t < 8; ++t) f[t] = sbuf[SW(tid + t * 512)];
#pragma unroll
        for (int t = 0; t < 8; t += 2) {
            float2 bb = cmul(f[t + 1], v3);
            float2 a = f[t];
            f[t]     = make_float2(a.x + bb.x, a.y + bb.y);
            f[t + 1] = make_float2(a.x - bb.x, a.y - bb.y);
        }
#pragma unroll
        for (int t0 = 0; t0 < 8; t0 += 4) {
#pragma unroll
            for (int t = 0; t < 2; ++t) {
                int i = t0 + t;
                float2 bb = cmul(f[i + 2], v2);
                if (t == 1) bb = make_float2(-bb.y, bb.x);
                float2 a = f[i];
                f[i]     = make_float2(a.x + bb.x, a.y + bb.y);
                f[i + 2] = make_float2(a.x - bb.x, a.y - bb.y);
            }
        }
#pragma unroll
        for (int t = 0; t < 4; ++t) {
            float2 bb = cmul(f[t + 4], v1);
            if (t == 1)      bb = make_float2(RSQ2 * (bb.x - bb.y), RSQ2 * (bb.x + bb.y));
            else if (t == 2) bb = make_float2(-bb.y, bb.x);
            else if (t == 3) bb = make_float2(-RSQ2 * (bb.x + bb.y), RSQ2 * (bb.x - bb.y));
            float2 a = f[t];
            f[t]     = make_float2(a.x + bb.x, a.y + bb.y);
            f[t + 4] = make_float2(a.x - bb.x, a.y - bb.y);
        }
#pragma unroll
        for (int t = 0; t < 8; ++t) b0[tid + t * 512] = f[t];
    }
}

// ---------------- k3: final h=4096 DIT stage, in place ----------------
__global__ __launch_bounds__(256)
void final_stage_kernel(float2* __restrict__ dout) {
    int idx = blockIdx.x * 256 + threadIdx.x;        // over 256*4096
    int r = idx >> 12;
    int u = idx & (HALF_TK - 1);
    float2* __restrict__ row = dout + (size_t)r * TK;
    float2 a = row[u];
    float2 b = row[u + HALF_TK];
    float2 w = g_W[u]; w.y = -w.y;
    b = cmul(b, w);
    row[u]           = make_float2(a.x + b.x, a.y + b.y);
    row[u + HALF_TK] = make_float2(a.x - b.x, a.y - b.y);
}

// ------------- fallback: single kernel (R2 structure + chain) -------------
__global__ __launch_bounds__(1024, 4)
void conv_fft_single(const float* __restrict__ x, float2* __restrict__ out) {
    __shared__ float2 buf[TK];
    const int tid = threadIdx.x;
    const int b = blockIdx.x;
    const float4* __restrict__ xrow4 =
        reinterpret_cast<const float4*>(x + (size_t)b * TFULL);

    float2 acc[8];
#pragma unroll
    for (int c = 0; c < 8; ++c) acc[c] = make_float2(0.f, 0.f);

    for (int j = 0; j < NPAIR; ++j) {
#pragma unroll
        for (int c4 = 0; c4 < 4; ++c4) {
            int u = c4 * 1024 + tid;
            float4 A = xrow4[2 * u + (j >> 1)];
            float4 B = xrow4[2 * (u + HALF_TK) + (j >> 1)];
            float2 a  = (j & 1) ? make_float2(A.z, A.w) : make_float2(A.x, A.y);
            float2 b2 = (j & 1) ? make_float2(B.z, B.w) : make_float2(B.x, B.y);
            stage1_store(buf, u, a, b2);
        }
        __syncthreads();
        fwd_pass<9>(buf, tid);
        __syncthreads();
        fwd_pass<6>(buf, tid);
        WAVE_SYNC();
        fwd_pass<3>(buf, tid);
        WAVE_SYNC();
        fwd_pass<0>(buf, tid);
        __syncthreads();
        const float2* __restrict__ P = g_P + (size_t)j * TK;
        const float2* __restrict__ Q = g_Q + (size_t)j * TK;
#pragma unroll
        for (int c = 0; c < 8; ++c) {
            int rr = 8 * tid + c;
            unsigned t = br13((unsigned)rr);
            unsigned tm = (TK - t) & (TK - 1);
            int r2 = (int)br13(tm);
            float2 Zt = buf[SW(rr)];
            float2 Zm = buf[SW(r2)];
            float2 Pv = P[rr], Qv = Q[rr];
            acc[c].x += Zt.x * Pv.x - Zt.y * Pv.y + Zm.x * Qv.x + Zm.y * Qv.y;
            acc[c].y += Zt.x * Pv.y + Zt.y * Pv.x + Zm.x * Qv.y - Zm.y * Qv.x;
        }
        __syncthreads();
    }

    {
        float2 e[8];
        reg_inv_c0(acc, e);
#pragma unroll
        for (int t = 0; t < 8; ++t) buf[SW(8 * tid + t)] = e[t];
    }
    __syncthreads();
    inv_pass<3>(buf, tid);
    WAVE_SYNC();
    inv_pass<6>(buf, tid);
    __syncthreads();
    inv_pass<9>(buf, tid);
    __syncthreads();
    float2* __restrict__ orow = out + (size_t)b * TK;
#pragma unroll
    for (int c4 = 0; c4 < 4; ++c4) {
        int u = c4 * 1024 + tid;
        float2 a = buf[SW(u)];
        float2 w = g_W[u]; w.y = -w.y;
        float2 bb = cmul(buf[SW(u + HALF_TK)], w);
        orow[u]           = make_float2(a.x + bb.x, a.y + bb.y);
        orow[u + HALF_TK] = make_float2(a.x - bb.x, a.y - bb.y);
    }
}

extern "C" void kernel_launch(void* const* d_in, const int* in_sizes, int n_in,
                              void* d_out, int out_size, void* d_ws, size_t ws_size,
                              hipStream_t stream) {
    const float* x    = (const float*)d_in[0];
    const float* filt = (const float*)d_in[1];
    const int T = in_sizes[1];          // 65536
    const int B = in_sizes[0] / T;      // 256 rows
    (void)n_in; (void)out_size; (void)T;

    build_twiddle_kernel<<<HALF_TK / 256, 256, 0, stream>>>();
    build_pq_kernel<<<TK / 256, 256, 0, stream>>>(filt);

    const size_t need = (size_t)B * TK * sizeof(float2);   // 16.78 MB partial buf
    if (ws_size >= need) {
        float2* ph0 = (float2*)d_out;
        float2* ph1 = (float2*)d_ws;
        fwd_half_kernel<<<2 * B, 1024, 0, stream>>>(x, ph0, ph1);
        inv_half_kernel<<<2 * B, 512, 0, stream>>>(ph0, ph1);
        final_stage_kernel<<<B * HALF_TK / 256, 256, 0, stream>>>(ph0);
    } else {
        conv_fft_single<<<B, 1024, 0, stream>>>(x, (float2*)d_out);
    }
}

// Round 10
// 114.046 us; speedup vs baseline: 1.3756x; 1.3756x over previous
//
#include <hip/hip_runtime.h>

// Conv1dFFT via polyphase: y[b] = IFFT_8192( sum_p G_p * FFT_8192(x_polyphase_p) )
// 3-kernel split for occupancy:
//  k1: 512 blocks (row,half) x 1024thr -> 2 fwd FFTs + P/Q partial acc
//      __launch_bounds__(1024,4): proven (R2) to yield VGPR=64, no spill;
//      64 VGPR + 64KB LDS lets HW co-schedule 2 WG/CU at runtime.
//  k2: 512 blocks (row,q) x 512thr -> sum partials + inverse C0..C9 on 4096-half
//  k3: streaming final h=4096 DIT stage in place
// Fallback single kernel if ws too small.

#define TK      8192
#define LOG2TK  13
#define HALF_TK 4096
#define KFOLD   8
#define NPAIR   4
#define TFULL   65536
#define RSQ2    0.70710678118654752440f

#define SW(i) ((i) ^ (((i) >> 4) & 15))

#define WAVE_SYNC() do { asm volatile("" ::: "memory"); __builtin_amdgcn_wave_barrier(); } while (0)

__device__ __forceinline__ float2 cmul(float2 a, float2 b) {
    return make_float2(a.x * b.x - a.y * b.y, a.x * b.y + a.y * b.x);
}
__device__ __forceinline__ unsigned br13(unsigned r) { return __brev(r) >> 19u; }

__device__ float2 g_W[HALF_TK];        // e^{-2pi i t/8192}
__device__ float2 g_P[NPAIR * TK];     // bit-reversed order
__device__ float2 g_Q[NPAIR * TK];     // bit-reversed order

__global__ void build_twiddle_kernel() {
    int t = blockIdx.x * blockDim.x + threadIdx.x;
    if (t < HALF_TK) {
        double ang = -2.0 * 3.14159265358979323846 * (double)t / (double)TK;
        g_W[t] = make_float2((float)cos(ang), (float)sin(ang));
    }
}

// All-float P/Q build: exact constant table for the 8-pt DFT factors,
// sincosf for the linear phase (|err| ~1e-7 << 0.056 threshold).
__global__ void build_pq_kernel(const float* __restrict__ filt) {
    int t = blockIdx.x * blockDim.x + threadIdx.x;
    if (t >= TK) return;
    // e^{-2pi i k/8} = c8[k] + i s8[k]
    const float c8[8] = { 1.f,  RSQ2,  0.f, -RSQ2, -1.f, -RSQ2,  0.f,  RSQ2 };
    const float s8[8] = { 0.f, -RSQ2, -1.f, -RSQ2,  0.f,  RSQ2,  1.f,  RSQ2 };
    float fm[KFOLD];
#pragma unroll
    for (int m = 0; m < KFOLD; ++m) fm[m] = filt[m * TK + t];
    float2 G[KFOLD];
#pragma unroll
    for (int p = 0; p < KFOLD; ++p) {
        float sr = 0.f, si = 0.f;
#pragma unroll
        for (int m = 0; m < KFOLD; ++m) {
            int k = (p * m) & 7;
            sr += fm[m] * c8[k];
            si += fm[m] * s8[k];
        }
        // G_p = e^{-2pi i p t / 65536} * S_p / 8
        float ang2 = -6.28318530717958647693f * (float)(p * t) / (float)TFULL;
        float c2, s2;
        __sincosf(ang2, &s2, &c2);
        G[p] = make_float2((sr * c2 - si * s2) * 0.125f,
                           (sr * s2 + si * c2) * 0.125f);
    }
    const float norm = 0.5f / (float)TK;
    unsigned r = br13((unsigned)t);
#pragma unroll
    for (int j = 0; j < NPAIR; ++j) {
        float2 g0 = G[2 * j], g1 = G[2 * j + 1];
        g_P[j * TK + r] = make_float2((g0.x + g1.y) * norm, (g0.y - g1.x) * norm);
        g_Q[j * TK + r] = make_float2((g0.x - g1.y) * norm, (g0.y + g1.x) * norm);
    }
}

// Forward DIF radix-8 pass: stages (4s, 2s, s), s = 1<<C. 1024 threads, 8192 pts.
template<int C>
__device__ __forceinline__ void fwd_pass(float2* buf, int tid) {
    const int s = 1 << C;
    const int q0 = tid & (s - 1);
    const int i0 = ((tid >> C) << (C + 3)) + q0;
    float2 e[8];
#pragma unroll
    for (int t = 0; t < 8; ++t) e[t] = buf[SW(i0 + t * s)];
    float2 w1, w2, w3;
    if (C == 0) { w1 = make_float2(1.f, 0.f); w2 = w1; w3 = w1; }
    else { w1 = g_W[q0 << (10 - C)]; w2 = cmul(w1, w1); w3 = cmul(w2, w2); }
#pragma unroll
    for (int t = 0; t < 4; ++t) {
        float2 a = e[t], b = e[t + 4];
        float2 d = make_float2(a.x - b.x, a.y - b.y);
        e[t] = make_float2(a.x + b.x, a.y + b.y);
        d = cmul(d, w1);
        if (t == 1)      d = make_float2(RSQ2 * (d.x + d.y), RSQ2 * (d.y - d.x));
        else if (t == 2) d = make_float2(d.y, -d.x);
        else if (t == 3) d = make_float2(RSQ2 * (d.y - d.x), -RSQ2 * (d.x + d.y));
        e[t + 4] = d;
    }
#pragma unroll
    for (int t0 = 0; t0 < 8; t0 += 4) {
#pragma unroll
        for (int t = 0; t < 2; ++t) {
            int i = t0 + t;
            float2 a = e[i], b = e[i + 2];
            float2 d = make_float2(a.x - b.x, a.y - b.y);
            e[i] = make_float2(a.x + b.x, a.y + b.y);
            d = cmul(d, w2);
            if (t == 1) d = make_float2(d.y, -d.x);
            e[i + 2] = d;
        }
    }
#pragma unroll
    for (int t = 0; t < 8; t += 2) {
        float2 a = e[t], b = e[t + 1];
        float2 d = make_float2(a.x - b.x, a.y - b.y);
        e[t] = make_float2(a.x + b.x, a.y + b.y);
        e[t + 1] = cmul(d, w3);
    }
#pragma unroll
    for (int t = 0; t < 8; ++t) buf[SW(i0 + t * s)] = e[t];
}

// Inverse DIT radix-8 pass: stages (s, 2s, 4s), conjugated twiddles.
template<int C>
__device__ __forceinline__ void inv_pass(float2* buf, int tid) {
    const int s = 1 << C;
    const int q0 = tid & (s - 1);
    const int i0 = ((tid >> C) << (C + 3)) + q0;
    float2 e[8];
#pragma unroll
    for (int t = 0; t < 8; ++t) e[t] = buf[SW(i0 + t * s)];
    float2 v1, v2, v3;
    if (C == 0) { v1 = make_float2(1.f, 0.f); v2 = v1; v3 = v1; }
    else { v1 = g_W[q0 << (10 - C)]; v1.y = -v1.y; v2 = cmul(v1, v1); v3 = cmul(v2, v2); }
#pragma unroll
    for (int t = 0; t < 8; t += 2) {
        float2 b = cmul(e[t + 1], v3);
        float2 a = e[t];
        e[t]     = make_float2(a.x + b.x, a.y + b.y);
        e[t + 1] = make_float2(a.x - b.x, a.y - b.y);
    }
#pragma unroll
    for (int t0 = 0; t0 < 8; t0 += 4) {
#pragma unroll
        for (int t = 0; t < 2; ++t) {
            int i = t0 + t;
            float2 b = cmul(e[i + 2], v2);
            if (t == 1) b = make_float2(-b.y, b.x);
            float2 a = e[i];
            e[i]     = make_float2(a.x + b.x, a.y + b.y);
            e[i + 2] = make_float2(a.x - b.x, a.y - b.y);
        }
    }
#pragma unroll
    for (int t = 0; t < 4; ++t) {
        float2 b = cmul(e[t + 4], v1);
        if (t == 1)      b = make_float2(RSQ2 * (b.x - b.y), RSQ2 * (b.x + b.y));
        else if (t == 2) b = make_float2(-b.y, b.x);
        else if (t == 3) b = make_float2(-RSQ2 * (b.x + b.y), RSQ2 * (b.x - b.y));
        float2 a = e[t];
        e[t]     = make_float2(a.x + b.x, a.y + b.y);
        e[t + 4] = make_float2(a.x - b.x, a.y - b.y);
    }
#pragma unroll
    for (int t = 0; t < 8; ++t) buf[SW(i0 + t * s)] = e[t];
}

// Register radix-8 inverse C=0 pass (unit group twiddle): acc[8] -> e[8]
__device__ __forceinline__ void reg_inv_c0(const float2* acc, float2* e) {
#pragma unroll
    for (int t = 0; t < 8; t += 2) {
        float2 a = acc[t], bb = acc[t + 1];
        e[t]     = make_float2(a.x + bb.x, a.y + bb.y);
        e[t + 1] = make_float2(a.x - bb.x, a.y - bb.y);
    }
#pragma unroll
    for (int t0 = 0; t0 < 8; t0 += 4) {
        {
            float2 a = e[t0], bb = e[t0 + 2];
            e[t0]     = make_float2(a.x + bb.x, a.y + bb.y);
            e[t0 + 2] = make_float2(a.x - bb.x, a.y - bb.y);
        }
        {
            float2 a = e[t0 + 1], bb = e[t0 + 3];
            bb = make_float2(-bb.y, bb.x);
            e[t0 + 1] = make_float2(a.x + bb.x, a.y + bb.y);
            e[t0 + 3] = make_float2(a.x - bb.x, a.y - bb.y);
        }
    }
#pragma unroll
    for (int t = 0; t < 4; ++t) {
        float2 bb = e[t + 4];
        if (t == 1)      bb = make_float2(RSQ2 * (bb.x - bb.y), RSQ2 * (bb.x + bb.y));
        else if (t == 2) bb = make_float2(-bb.y, bb.x);
        else if (t == 3) bb = make_float2(-RSQ2 * (bb.x + bb.y), RSQ2 * (bb.x - bb.y));
        float2 a = e[t];
        e[t]     = make_float2(a.x + bb.x, a.y + bb.y);
        e[t + 4] = make_float2(a.x - bb.x, a.y - bb.y);
    }
}

__device__ __forceinline__ void stage1_store(float2* buf, int u, float2 a, float2 b2) {
    float2 w = g_W[u];
    buf[SW(u)] = make_float2(a.x + b2.x, a.y + b2.y);
    buf[SW(u + HALF_TK)] = cmul(make_float2(a.x - b2.x, a.y - b2.y), w);
}

// ---------------- k1: forward FFTs for one (row, half) ----------------
__global__ __launch_bounds__(1024, 4)   // (1024,4) -> VGPR=64 no-spill (R2-proven)
void fwd_half_kernel(const float* __restrict__ x,
                     float2* __restrict__ ph0, float2* __restrict__ ph1) {
    __shared__ float2 buf[TK];   // 64 KB
    const int tid = threadIdx.x;
    const int r = blockIdx.x >> 1;
    const int h = blockIdx.x & 1;
    const float4* __restrict__ xrow4 =
        reinterpret_cast<const float4*>(x + (size_t)r * TFULL);

    float2 acc[8];
#pragma unroll
    for (int c = 0; c < 8; ++c) acc[c] = make_float2(0.f, 0.f);

    for (int jj = 0; jj < 2; ++jj) {          // j = 2h + jj
        // load + first DIF stage (h=4096). Same float4s both jj -> 2nd pass L2-hit.
#pragma unroll
        for (int c4 = 0; c4 < 4; ++c4) {
            int u = c4 * 1024 + tid;
            float4 A = xrow4[2 * u + h];
            float4 B = xrow4[2 * (u + HALF_TK) + h];
            float2 a  = jj ? make_float2(A.z, A.w) : make_float2(A.x, A.y);
            float2 b2 = jj ? make_float2(B.z, B.w) : make_float2(B.x, B.y);
            stage1_store(buf, u, a, b2);
        }
        __syncthreads();
        fwd_pass<9>(buf, tid);
        __syncthreads();
        fwd_pass<6>(buf, tid);
        WAVE_SYNC();
        fwd_pass<3>(buf, tid);
        WAVE_SYNC();
        fwd_pass<0>(buf, tid);
        __syncthreads();
        const int j = 2 * h + jj;
        const float2* __restrict__ P = g_P + (size_t)j * TK;
        const float2* __restrict__ Q = g_Q + (size_t)j * TK;
#pragma unroll
        for (int c = 0; c < 8; ++c) {
            int rr = 8 * tid + c;
            unsigned t = br13((unsigned)rr);
            unsigned tm = (TK - t) & (TK - 1);
            int r2 = (int)br13(tm);
            float2 Zt = buf[SW(rr)];
            float2 Zm = buf[SW(r2)];
            float2 Pv = P[rr], Qv = Q[rr];
            acc[c].x += Zt.x * Pv.x - Zt.y * Pv.y + Zm.x * Qv.x + Zm.y * Qv.y;
            acc[c].y += Zt.x * Pv.y + Zt.y * Pv.x + Zm.x * Qv.y - Zm.y * Qv.x;
        }
        __syncthreads();
    }
    float2* __restrict__ dst = (h ? ph1 : ph0) + (size_t)r * TK;
#pragma unroll
    for (int c = 0; c < 8; ++c) dst[8 * tid + c] = acc[c];
}

// ------- k2: sum partials + inverse C0,C3,C6,C9 on one 4096-half -------
__global__ __launch_bounds__(512, 4)
void inv_half_kernel(float2* __restrict__ ph0, const float2* __restrict__ ph1) {
    __shared__ float2 sbuf[HALF_TK];   // 32 KB
    const int tid = threadIdx.x;
    const int r = blockIdx.x >> 1;
    const int q = blockIdx.x & 1;
    float2* __restrict__ b0 = ph0 + (size_t)r * TK + q * HALF_TK;
    const float2* __restrict__ b1 = ph1 + (size_t)r * TK + q * HALF_TK;

    float2 acc[8];
#pragma unroll
    for (int c = 0; c < 8; ++c) {
        int l = 8 * tid + c;
        float2 a0 = b0[l], a1 = b1[l];
        acc[c] = make_float2(a0.x + a1.x, a0.y + a1.y);
    }
    float2 e[8];
    reg_inv_c0(acc, e);
#pragma unroll
    for (int t = 0; t < 8; ++t) sbuf[SW(8 * tid + t)] = e[t];
    WAVE_SYNC();
    inv_pass<3>(sbuf, tid);   // half-local; twiddles depend only on i mod h
    WAVE_SYNC();
    inv_pass<6>(sbuf, tid);
    __syncthreads();
    // C9 (stages 512,1024,2048) computed in regs, stored straight to global
    {
        float2 v1 = g_W[tid << 1]; v1.y = -v1.y;
        float2 v2 = cmul(v1, v1), v3 = cmul(v2, v2);
        float2 f[8];
#pragma unroll
        for (int t = 0; t < 8; ++t) f[t] = sbuf[SW(tid + t * 512)];
#pragma unroll
        for (int t = 0; t < 8; t += 2) {
            float2 bb = cmul(f[t + 1], v3);
            float2 a = f[t];
            f[t]     = make_float2(a.x + bb.x, a.y + bb.y);
            f[t + 1] = make_float2(a.x - bb.x, a.y - bb.y);
        }
#pragma unroll
        for (int t0 = 0; t0 < 8; t0 += 4) {
#pragma unroll
            for (int t = 0; t < 2; ++t) {
                int i = t0 + t;
                float2 bb = cmul(f[i + 2], v2);
                if (t == 1) bb = make_float2(-bb.y, bb.x);
                float2 a = f[i];
                f[i]     = make_float2(a.x + bb.x, a.y + bb.y);
                f[i + 2] = make_float2(a.x - bb.x, a.y - bb.y);
            }
        }
#pragma unroll
        for (int t = 0; t < 4; ++t) {
            float2 bb = cmul(f[t + 4], v1);
            if (t == 1)      bb = make_float2(RSQ2 * (bb.x - bb.y), RSQ2 * (bb.x + bb.y));
            else if (t == 2) bb = make_float2(-bb.y, bb.x);
            else if (t == 3) bb = make_float2(-RSQ2 * (bb.x + bb.y), RSQ2 * (bb.x - bb.y));
            float2 a = f[t];
            f[t]     = make_float2(a.x + bb.x, a.y + bb.y);
            f[t + 4] = make_float2(a.x - bb.x, a.y - bb.y);
        }
#pragma unroll
        for (int t = 0; t < 8; ++t) b0[tid + t * 512] = f[t];
    }
}

// ---------------- k3: final h=4096 DIT stage, in place ----------------
__global__ __launch_bounds__(256)
void final_stage_kernel(float2* __restrict__ dout) {
    int idx = blockIdx.x * 256 + threadIdx.x;        // over 256*4096
    int r = idx >> 12;
    int u = idx & (HALF_TK - 1);
    float2* __restrict__ row = dout + (size_t)r * TK;
    float2 a = row[u];
    float2 b = row[u + HALF_TK];
    float2 w = g_W[u]; w.y = -w.y;
    b = cmul(b, w);
    row[u]           = make_float2(a.x + b.x, a.y + b.y);
    row[u + HALF_TK] = make_float2(a.x - b.x, a.y - b.y);
}

// ------------- fallback: single kernel (R2 structure + chain) -------------
__global__ __launch_bounds__(1024, 4)
void conv_fft_single(const float* __restrict__ x, float2* __restrict__ out) {
    __shared__ float2 buf[TK];
    const int tid = threadIdx.x;
    const int b = blockIdx.x;
    const float4* __restrict__ xrow4 =
        reinterpret_cast<const float4*>(x + (size_t)b * TFULL);

    float2 acc[8];
#pragma unroll
    for (int c = 0; c < 8; ++c) acc[c] = make_float2(0.f, 0.f);

    for (int j = 0; j < NPAIR; ++j) {
#pragma unroll
        for (int c4 = 0; c4 < 4; ++c4) {
            int u = c4 * 1024 + tid;
            float4 A = xrow4[2 * u + (j >> 1)];
            float4 B = xrow4[2 * (u + HALF_TK) + (j >> 1)];
            float2 a  = (j & 1) ? make_float2(A.z, A.w) : make_float2(A.x, A.y);
            float2 b2 = (j & 1) ? make_float2(B.z, B.w) : make_float2(B.x, B.y);
            stage1_store(buf, u, a, b2);
        }
        __syncthreads();
        fwd_pass<9>(buf, tid);
        __syncthreads();
        fwd_pass<6>(buf, tid);
        WAVE_SYNC();
        fwd_pass<3>(buf, tid);
        WAVE_SYNC();
        fwd_pass<0>(buf, tid);
        __syncthreads();
        const float2* __restrict__ P = g_P + (size_t)j * TK;
        const float2* __restrict__ Q = g_Q + (size_t)j * TK;
#pragma unroll
        for (int c = 0; c < 8; ++c) {
            int rr = 8 * tid + c;
            unsigned t = br13((unsigned)rr);
            unsigned tm = (TK - t) & (TK - 1);
            int r2 = (int)br13(tm);
            float2 Zt = buf[SW(rr)];
            float2 Zm = buf[SW(r2)];
            float2 Pv = P[rr], Qv = Q[rr];
            acc[c].x += Zt.x * Pv.x - Zt.y * Pv.y + Zm.x * Qv.x + Zm.y * Qv.y;
            acc[c].y += Zt.x * Pv.y + Zt.y * Pv.x + Zm.x * Qv.y - Zm.y * Qv.x;
        }
        __syncthreads();
    }

    {
        float2 e[8];
        reg_inv_c0(acc, e);
#pragma unroll
        for (int t = 0; t < 8; ++t) buf[SW(8 * tid + t)] = e[t];
    }
    __syncthreads();
    inv_pass<3>(buf, tid);
    WAVE_SYNC();
    inv_pass<6>(buf, tid);
    __syncthreads();
    inv_pass<9>(buf, tid);
    __syncthreads();
    float2* __restrict__ orow = out + (size_t)b * TK;
#pragma unroll
    for (int c4 = 0; c4 < 4; ++c4) {
        int u = c4 * 1024 + tid;
        float2 a = buf[SW(u)];
        float2 w = g_W[u]; w.y = -w.y;
        float2 bb = cmul(buf[SW(u + HALF_TK)], w);
        orow[u]           = make_float2(a.x + bb.x, a.y + bb.y);
        orow[u + HALF_TK] = make_float2(a.x - bb.x, a.y - bb.y);
    }
}

extern "C" void kernel_launch(void* const* d_in, const int* in_sizes, int n_in,
                              void* d_out, int out_size, void* d_ws, size_t ws_size,
                              hipStream_t stream) {
    const float* x    = (const float*)d_in[0];
    const float* filt = (const float*)d_in[1];
    const int T = in_sizes[1];          // 65536
    const int B = in_sizes[0] / T;      // 256 rows
    (void)n_in; (void)out_size; (void)T;

    build_twiddle_kernel<<<HALF_TK / 256, 256, 0, stream>>>();
    build_pq_kernel<<<TK / 256, 256, 0, stream>>>(filt);

    const size_t need = (size_t)B * TK * sizeof(float2);   // 16.78 MB partial buf
    if (ws_size >= need) {
        float2* ph0 = (float2*)d_out;
        float2* ph1 = (float2*)d_ws;
        fwd_half_kernel<<<2 * B, 1024, 0, stream>>>(x, ph0, ph1);
        inv_half_kernel<<<2 * B, 512, 0, stream>>>(ph0, ph1);
        final_stage_kernel<<<B * HALF_TK / 256, 256, 0, stream>>>(ph0);
    } else {
        conv_fft_single<<<B, 1024, 0, stream>>>(x, (float2*)d_out);
    }
}

// Round 11
// 107.937 us; speedup vs baseline: 1.4535x; 1.0566x over previous
//
#include <hip/hip_runtime.h>

// Conv1dFFT via polyphase: y[b] = IFFT_8192( sum_p G_p * FFT_8192(x_polyphase_p) )
// R4/R5 paired structure (two FFTs per barrier region, 128 KB LDS, wave-chained
// passes, register inverse-C0 tail) + amdgpu_waves_per_eu(4,4) so the register
// allocator targets 4 waves/EU (1 WG/CU) and may use ~128 VGPRs -> no spill
// (R5 failure mode: allocator pinned 64 VGPR and spilled ~100 MB to scratch).

#define TK      8192
#define LOG2TK  13
#define HALF_TK 4096
#define KFOLD   8
#define NPAIR   4
#define TFULL   65536
#define NT      1024
#define RSQ2    0.70710678118654752440f

// LDS bank-conflict swizzle (bijective: low 4 bits XOR bits 4..7)
#define SW(i) ((i) ^ (((i) >> 4) & 15))

// Compiler-only ordering fence for wave-synchronous LDS hand-offs.
#define WAVE_SYNC() do { asm volatile("" ::: "memory"); __builtin_amdgcn_wave_barrier(); } while (0)

__device__ __forceinline__ float2 cmul(float2 a, float2 b) {
    return make_float2(a.x * b.x - a.y * b.y, a.x * b.y + a.y * b.x);
}
__device__ __forceinline__ unsigned br13(unsigned r) { return __brev(r) >> 19u; }

__device__ float2 g_W[HALF_TK];        // e^{-2pi i t/8192}
__device__ float2 g_P[NPAIR * TK];     // bit-reversed order
__device__ float2 g_Q[NPAIR * TK];     // bit-reversed order

__global__ void build_twiddle_kernel() {
    int t = blockIdx.x * blockDim.x + threadIdx.x;
    if (t < HALF_TK) {
        double ang = -2.0 * 3.14159265358979323846 * (double)t / (double)TK;
        g_W[t] = make_float2((float)cos(ang), (float)sin(ang));
    }
}

// All-float P/Q build (validated R7-R10): exact 8-pt DFT constants + sincosf.
__global__ void build_pq_kernel(const float* __restrict__ filt) {
    int t = blockIdx.x * blockDim.x + threadIdx.x;
    if (t >= TK) return;
    const float c8[8] = { 1.f,  RSQ2,  0.f, -RSQ2, -1.f, -RSQ2,  0.f,  RSQ2 };
    const float s8[8] = { 0.f, -RSQ2, -1.f, -RSQ2,  0.f,  RSQ2,  1.f,  RSQ2 };
    float fm[KFOLD];
#pragma unroll
    for (int m = 0; m < KFOLD; ++m) fm[m] = filt[m * TK + t];
    float2 G[KFOLD];
#pragma unroll
    for (int p = 0; p < KFOLD; ++p) {
        float sr = 0.f, si = 0.f;
#pragma unroll
        for (int m = 0; m < KFOLD; ++m) {
            int k = (p * m) & 7;
            sr += fm[m] * c8[k];
            si += fm[m] * s8[k];
        }
        float ang2 = -6.28318530717958647693f * (float)(p * t) / (float)TFULL;
        float c2, s2;
        __sincosf(ang2, &s2, &c2);
        G[p] = make_float2((sr * c2 - si * s2) * 0.125f,
                           (sr * s2 + si * c2) * 0.125f);
    }
    const float norm = 0.5f / (float)TK;
    unsigned r = br13((unsigned)t);
#pragma unroll
    for (int j = 0; j < NPAIR; ++j) {
        float2 g0 = G[2 * j], g1 = G[2 * j + 1];
        g_P[j * TK + r] = make_float2((g0.x + g1.y) * norm, (g0.y - g1.x) * norm);
        g_Q[j * TK + r] = make_float2((g0.x - g1.y) * norm, (g0.y + g1.x) * norm);
    }
}

// Forward DIF radix-8 pass: stages (4s, 2s, s), s = 1<<C.
template<int C>
__device__ __forceinline__ void fwd_pass(float2* buf, int tid) {
    const int s = 1 << C;
    const int q0 = tid & (s - 1);
    const int i0 = ((tid >> C) << (C + 3)) + q0;
    float2 e[8];
#pragma unroll
    for (int t = 0; t < 8; ++t) e[t] = buf[SW(i0 + t * s)];
    float2 w1, w2, w3;
    if (C == 0) { w1 = make_float2(1.f, 0.f); w2 = w1; w3 = w1; }
    else { w1 = g_W[q0 << (10 - C)]; w2 = cmul(w1, w1); w3 = cmul(w2, w2); }
#pragma unroll
    for (int t = 0; t < 4; ++t) {
        float2 a = e[t], b = e[t + 4];
        float2 d = make_float2(a.x - b.x, a.y - b.y);
        e[t] = make_float2(a.x + b.x, a.y + b.y);
        d = cmul(d, w1);
        if (t == 1)      d = make_float2(RSQ2 * (d.x + d.y), RSQ2 * (d.y - d.x));
        else if (t == 2) d = make_float2(d.y, -d.x);
        else if (t == 3) d = make_float2(RSQ2 * (d.y - d.x), -RSQ2 * (d.x + d.y));
        e[t + 4] = d;
    }
#pragma unroll
    for (int t0 = 0; t0 < 8; t0 += 4) {
#pragma unroll
        for (int t = 0; t < 2; ++t) {
            int i = t0 + t;
            float2 a = e[i], b = e[i + 2];
            float2 d = make_float2(a.x - b.x, a.y - b.y);
            e[i] = make_float2(a.x + b.x, a.y + b.y);
            d = cmul(d, w2);
            if (t == 1) d = make_float2(d.y, -d.x);
            e[i + 2] = d;
        }
    }
#pragma unroll
    for (int t = 0; t < 8; t += 2) {
        float2 a = e[t], b = e[t + 1];
        float2 d = make_float2(a.x - b.x, a.y - b.y);
        e[t] = make_float2(a.x + b.x, a.y + b.y);
        e[t + 1] = cmul(d, w3);
    }
#pragma unroll
    for (int t = 0; t < 8; ++t) buf[SW(i0 + t * s)] = e[t];
}

// Inverse DIT radix-8 pass: stages (s, 2s, 4s), conjugated twiddles.
template<int C>
__device__ __forceinline__ void inv_pass(float2* buf, int tid) {
    const int s = 1 << C;
    const int q0 = tid & (s - 1);
    const int i0 = ((tid >> C) << (C + 3)) + q0;
    float2 e[8];
#pragma unroll
    for (int t = 0; t < 8; ++t) e[t] = buf[SW(i0 + t * s)];
    float2 v1, v2, v3;
    if (C == 0) { v1 = make_float2(1.f, 0.f); v2 = v1; v3 = v1; }
    else { v1 = g_W[q0 << (10 - C)]; v1.y = -v1.y; v2 = cmul(v1, v1); v3 = cmul(v2, v2); }
#pragma unroll
    for (int t = 0; t < 8; t += 2) {
        float2 b = cmul(e[t + 1], v3);
        float2 a = e[t];
        e[t]     = make_float2(a.x + b.x, a.y + b.y);
        e[t + 1] = make_float2(a.x - b.x, a.y - b.y);
    }
#pragma unroll
    for (int t0 = 0; t0 < 8; t0 += 4) {
#pragma unroll
        for (int t = 0; t < 2; ++t) {
            int i = t0 + t;
            float2 b = cmul(e[i + 2], v2);
            if (t == 1) b = make_float2(-b.y, b.x);
            float2 a = e[i];
            e[i]     = make_float2(a.x + b.x, a.y + b.y);
            e[i + 2] = make_float2(a.x - b.x, a.y - b.y);
        }
    }
#pragma unroll
    for (int t = 0; t < 4; ++t) {
        float2 b = cmul(e[t + 4], v1);
        if (t == 1)      b = make_float2(RSQ2 * (b.x - b.y), RSQ2 * (b.x + b.y));
        else if (t == 2) b = make_float2(-b.y, b.x);
        else if (t == 3) b = make_float2(-RSQ2 * (b.x + b.y), RSQ2 * (b.x - b.y));
        float2 a = e[t];
        e[t]     = make_float2(a.x + b.x, a.y + b.y);
        e[t + 4] = make_float2(a.x - b.x, a.y - b.y);
    }
#pragma unroll
    for (int t = 0; t < 8; ++t) buf[SW(i0 + t * s)] = e[t];
}

__global__ __launch_bounds__(NT)
__attribute__((amdgpu_waves_per_eu(4, 4)))   // target EXACTLY 4 waves/EU -> VGPR budget 128, no spill
void conv_fft_kernel(const float* __restrict__ x, float2* __restrict__ out) {
    __shared__ float2 smem[2 * TK];           // 128 KB static: two 8192-pt buffers
    float2* bufA = smem;
    float2* bufB = smem + TK;
    const int tid = threadIdx.x;
    const int b = blockIdx.x;
    const float4* __restrict__ xrow4 =
        reinterpret_cast<const float4*>(x + (size_t)b * TFULL);

    float2 acc[8];
#pragma unroll
    for (int c = 0; c < 8; ++c) acc[c] = make_float2(0.f, 0.f);

    for (int jp = 0; jp < 2; ++jp) {          // FFT pair: j = 2jp (A), 2jp+1 (B)
        // global float4 load fused with first DIF stage (h = 4096), both buffers
#pragma unroll
        for (int c4 = 0; c4 < 4; ++c4) {
            int u = c4 * NT + tid;
            float4 a  = xrow4[2 * u + jp];                 // (reA,imA,reB,imB) @ u
            float4 b2 = xrow4[2 * (u + HALF_TK) + jp];     // @ u+4096
            float2 w = g_W[u];
            bufA[SW(u)] = make_float2(a.x + b2.x, a.y + b2.y);
            bufA[SW(u + HALF_TK)] = cmul(make_float2(a.x - b2.x, a.y - b2.y), w);
            bufB[SW(u)] = make_float2(a.z + b2.z, a.w + b2.w);
            bufB[SW(u + HALF_TK)] = cmul(make_float2(a.z - b2.z, a.w - b2.w), w);
        }
        __syncthreads();
        fwd_pass<9>(bufA, tid); fwd_pass<9>(bufB, tid);
        __syncthreads();
        // C6 -> C3 -> C0 communicate only within a wave: compiler fence only
        fwd_pass<6>(bufA, tid); fwd_pass<6>(bufB, tid);
        WAVE_SYNC();
        fwd_pass<3>(bufA, tid); fwd_pass<3>(bufB, tid);
        WAVE_SYNC();
        fwd_pass<0>(bufA, tid); fwd_pass<0>(bufB, tid);
        __syncthreads();
        // accumulate at r = 8*tid + c: y_hat += Z*P + conj(Z[-t])*Q
        const float2* __restrict__ PA = g_P + (size_t)(2 * jp) * TK;
        const float2* __restrict__ QA = g_Q + (size_t)(2 * jp) * TK;
        const float2* __restrict__ PB = g_P + (size_t)(2 * jp + 1) * TK;
        const float2* __restrict__ QB = g_Q + (size_t)(2 * jp + 1) * TK;
#pragma unroll
        for (int c = 0; c < 8; ++c) {
            int r = 8 * tid + c;
            unsigned t = br13((unsigned)r);
            unsigned tm = (TK - t) & (TK - 1);
            int r2 = (int)br13(tm);
            float2 ZtA = bufA[SW(r)], ZmA = bufA[SW(r2)];
            float2 ZtB = bufB[SW(r)], ZmB = bufB[SW(r2)];
            float2 Pa = PA[r], Qa = QA[r], Pb = PB[r], Qb = QB[r];
            acc[c].x += ZtA.x * Pa.x - ZtA.y * Pa.y + ZmA.x * Qa.x + ZmA.y * Qa.y
                      + ZtB.x * Pb.x - ZtB.y * Pb.y + ZmB.x * Qb.x + ZmB.y * Qb.y;
            acc[c].y += ZtA.x * Pa.y + ZtA.y * Pa.x + ZmA.x * Qa.y - ZmA.y * Qa.x
                      + ZtB.x * Pb.y + ZtB.y * Pb.x + ZmB.x * Qb.y - ZmB.y * Qb.x;
        }
        __syncthreads();
    }

    // First inverse radix-8 pass (C=0, unit twiddles) in registers:
    // thread tid owns y_hat_br[8*tid .. 8*tid+8) == acc[0..8)  (validated R5)
    {
        float2 e[8];
        // stage h = 1
#pragma unroll
        for (int t = 0; t < 8; t += 2) {
            float2 a = acc[t], bb = acc[t + 1];
            e[t]     = make_float2(a.x + bb.x, a.y + bb.y);
            e[t + 1] = make_float2(a.x - bb.x, a.y - bb.y);
        }
        // stage h = 2 (twiddle (+i)^(t&1))
#pragma unroll
        for (int t0 = 0; t0 < 8; t0 += 4) {
            {
                float2 a = e[t0], bb = e[t0 + 2];
                e[t0]     = make_float2(a.x + bb.x, a.y + bb.y);
                e[t0 + 2] = make_float2(a.x - bb.x, a.y - bb.y);
            }
            {
                float2 a = e[t0 + 1], bb = e[t0 + 3];
                bb = make_float2(-bb.y, bb.x);
                e[t0 + 1] = make_float2(a.x + bb.x, a.y + bb.y);
                e[t0 + 3] = make_float2(a.x - bb.x, a.y - bb.y);
            }
        }
        // stage h = 4 (twiddle conj(u8)^t)
#pragma unroll
        for (int t = 0; t < 4; ++t) {
            float2 bb = e[t + 4];
            if (t == 1)      bb = make_float2(RSQ2 * (bb.x - bb.y), RSQ2 * (bb.x + bb.y));
            else if (t == 2) bb = make_float2(-bb.y, bb.x);
            else if (t == 3) bb = make_float2(-RSQ2 * (bb.x + bb.y), RSQ2 * (bb.x - bb.y));
            float2 a = e[t];
            e[t]     = make_float2(a.x + bb.x, a.y + bb.y);
            e[t + 4] = make_float2(a.x - bb.x, a.y - bb.y);
        }
#pragma unroll
        for (int t = 0; t < 8; ++t) bufA[SW(8 * tid + t)] = e[t];
    }
    WAVE_SYNC();
    // C0 -> C3 -> C6 same-wave; barrier before the cross-wave C9
    inv_pass<3>(bufA, tid);
    WAVE_SYNC();
    inv_pass<6>(bufA, tid);
    __syncthreads();
    inv_pass<9>(bufA, tid);
    __syncthreads();
    // final DIT stage (h = 4096) fused with global store
    float2* __restrict__ orow = out + (size_t)b * TK;
#pragma unroll
    for (int c4 = 0; c4 < 4; ++c4) {
        int u = c4 * NT + tid;
        float2 a = bufA[SW(u)];
        float2 w = g_W[u]; w.y = -w.y;
        float2 bb = cmul(bufA[SW(u + HALF_TK)], w);
        orow[u]           = make_float2(a.x + bb.x, a.y + bb.y);
        orow[u + HALF_TK] = make_float2(a.x - bb.x, a.y - bb.y);
    }
}

extern "C" void kernel_launch(void* const* d_in, const int* in_sizes, int n_in,
                              void* d_out, int out_size, void* d_ws, size_t ws_size,
                              hipStream_t stream) {
    const float* x    = (const float*)d_in[0];
    const float* filt = (const float*)d_in[1];
    const int T = in_sizes[1];          // 65536
    const int B = in_sizes[0] / T;      // 256 rows
    (void)n_in; (void)d_ws; (void)ws_size; (void)out_size; (void)T;

    build_twiddle_kernel<<<HALF_TK / 256, 256, 0, stream>>>();
    build_pq_kernel<<<TK / 256, 256, 0, stream>>>(filt);
    conv_fft_kernel<<<B, NT, 0, stream>>>(x, (float2*)d_out);
}

// Round 12
// 86.145 us; speedup vs baseline: 1.8212x; 1.2530x over previous
//
#include <hip/hip_runtime.h>

// Conv1dFFT via polyphase: y[b] = IFFT_8192( sum_p G_p * FFT_8192(x_polyphase_p) )
// Paired structure (two FFTs per barrier region, 128 KB LDS, wave-chained
// passes, register inverse-C0 tail) with sched_barrier(0) fences between the
// A and B pass bodies so their e[8] live ranges are DISJOINT -> fits the
// 64-VGPR allocation hipcc pins for 1024-thread blocks (R5/R11 spilled because
// the scheduler interleaved A and B).

#define TK      8192
#define LOG2TK  13
#define HALF_TK 4096
#define KFOLD   8
#define NPAIR   4
#define TFULL   65536
#define NT      1024
#define RSQ2    0.70710678118654752440f

// LDS bank-conflict swizzle (bijective: low 4 bits XOR bits 4..7)
#define SW(i) ((i) ^ (((i) >> 4) & 15))

// Compiler-only ordering fence for wave-synchronous LDS hand-offs.
#define WAVE_SYNC() do { asm volatile("" ::: "memory"); __builtin_amdgcn_wave_barrier(); } while (0)
// Scheduling fence: nothing crosses; pins A-pass before B-pass so register
// live ranges don't overlap. Emits no instructions.
#define SCHED_FENCE() __builtin_amdgcn_sched_barrier(0)

__device__ __forceinline__ float2 cmul(float2 a, float2 b) {
    return make_float2(a.x * b.x - a.y * b.y, a.x * b.y + a.y * b.x);
}
__device__ __forceinline__ unsigned br13(unsigned r) { return __brev(r) >> 19u; }

__device__ float2 g_W[HALF_TK];        // e^{-2pi i t/8192}
__device__ float2 g_P[NPAIR * TK];     // bit-reversed order
__device__ float2 g_Q[NPAIR * TK];     // bit-reversed order

__global__ void build_twiddle_kernel() {
    int t = blockIdx.x * blockDim.x + threadIdx.x;
    if (t < HALF_TK) {
        float ang = -6.28318530717958647693f * (float)t / (float)TK;
        float c, s;
        __sincosf(ang, &s, &c);
        g_W[t] = make_float2(c, s);
    }
}

// All-float P/Q build (validated R7-R11): exact 8-pt DFT constants + sincosf.
__global__ void build_pq_kernel(const float* __restrict__ filt) {
    int t = blockIdx.x * blockDim.x + threadIdx.x;
    if (t >= TK) return;
    const float c8[8] = { 1.f,  RSQ2,  0.f, -RSQ2, -1.f, -RSQ2,  0.f,  RSQ2 };
    const float s8[8] = { 0.f, -RSQ2, -1.f, -RSQ2,  0.f,  RSQ2,  1.f,  RSQ2 };
    float fm[KFOLD];
#pragma unroll
    for (int m = 0; m < KFOLD; ++m) fm[m] = filt[m * TK + t];
    float2 G[KFOLD];
#pragma unroll
    for (int p = 0; p < KFOLD; ++p) {
        float sr = 0.f, si = 0.f;
#pragma unroll
        for (int m = 0; m < KFOLD; ++m) {
            int k = (p * m) & 7;
            sr += fm[m] * c8[k];
            si += fm[m] * s8[k];
        }
        float ang2 = -6.28318530717958647693f * (float)(p * t) / (float)TFULL;
        float c2, s2;
        __sincosf(ang2, &s2, &c2);
        G[p] = make_float2((sr * c2 - si * s2) * 0.125f,
                           (sr * s2 + si * c2) * 0.125f);
    }
    const float norm = 0.5f / (float)TK;
    unsigned r = br13((unsigned)t);
#pragma unroll
    for (int j = 0; j < NPAIR; ++j) {
        float2 g0 = G[2 * j], g1 = G[2 * j + 1];
        g_P[j * TK + r] = make_float2((g0.x + g1.y) * norm, (g0.y - g1.x) * norm);
        g_Q[j * TK + r] = make_float2((g0.x - g1.y) * norm, (g0.y + g1.x) * norm);
    }
}

// Forward DIF radix-8 pass: stages (4s, 2s, s), s = 1<<C.
template<int C>
__device__ __forceinline__ void fwd_pass(float2* buf, int tid) {
    const int s = 1 << C;
    const int q0 = tid & (s - 1);
    const int i0 = ((tid >> C) << (C + 3)) + q0;
    float2 e[8];
#pragma unroll
    for (int t = 0; t < 8; ++t) e[t] = buf[SW(i0 + t * s)];
    float2 w1, w2, w3;
    if (C == 0) { w1 = make_float2(1.f, 0.f); w2 = w1; w3 = w1; }
    else { w1 = g_W[q0 << (10 - C)]; w2 = cmul(w1, w1); w3 = cmul(w2, w2); }
#pragma unroll
    for (int t = 0; t < 4; ++t) {
        float2 a = e[t], b = e[t + 4];
        float2 d = make_float2(a.x - b.x, a.y - b.y);
        e[t] = make_float2(a.x + b.x, a.y + b.y);
        d = cmul(d, w1);
        if (t == 1)      d = make_float2(RSQ2 * (d.x + d.y), RSQ2 * (d.y - d.x));
        else if (t == 2) d = make_float2(d.y, -d.x);
        else if (t == 3) d = make_float2(RSQ2 * (d.y - d.x), -RSQ2 * (d.x + d.y));
        e[t + 4] = d;
    }
#pragma unroll
    for (int t0 = 0; t0 < 8; t0 += 4) {
#pragma unroll
        for (int t = 0; t < 2; ++t) {
            int i = t0 + t;
            float2 a = e[i], b = e[i + 2];
            float2 d = make_float2(a.x - b.x, a.y - b.y);
            e[i] = make_float2(a.x + b.x, a.y + b.y);
            d = cmul(d, w2);
            if (t == 1) d = make_float2(d.y, -d.x);
            e[i + 2] = d;
        }
    }
#pragma unroll
    for (int t = 0; t < 8; t += 2) {
        float2 a = e[t], b = e[t + 1];
        float2 d = make_float2(a.x - b.x, a.y - b.y);
        e[t] = make_float2(a.x + b.x, a.y + b.y);
        e[t + 1] = cmul(d, w3);
    }
#pragma unroll
    for (int t = 0; t < 8; ++t) buf[SW(i0 + t * s)] = e[t];
}

// Inverse DIT radix-8 pass: stages (s, 2s, 4s), conjugated twiddles.
template<int C>
__device__ __forceinline__ void inv_pass(float2* buf, int tid) {
    const int s = 1 << C;
    const int q0 = tid & (s - 1);
    const int i0 = ((tid >> C) << (C + 3)) + q0;
    float2 e[8];
#pragma unroll
    for (int t = 0; t < 8; ++t) e[t] = buf[SW(i0 + t * s)];
    float2 v1, v2, v3;
    if (C == 0) { v1 = make_float2(1.f, 0.f); v2 = v1; v3 = v1; }
    else { v1 = g_W[q0 << (10 - C)]; v1.y = -v1.y; v2 = cmul(v1, v1); v3 = cmul(v2, v2); }
#pragma unroll
    for (int t = 0; t < 8; t += 2) {
        float2 b = cmul(e[t + 1], v3);
        float2 a = e[t];
        e[t]     = make_float2(a.x + b.x, a.y + b.y);
        e[t + 1] = make_float2(a.x - b.x, a.y - b.y);
    }
#pragma unroll
    for (int t0 = 0; t0 < 8; t0 += 4) {
#pragma unroll
        for (int t = 0; t < 2; ++t) {
            int i = t0 + t;
            float2 b = cmul(e[i + 2], v2);
            if (t == 1) b = make_float2(-b.y, b.x);
            float2 a = e[i];
            e[i]     = make_float2(a.x + b.x, a.y + b.y);
            e[i + 2] = make_float2(a.x - b.x, a.y - b.y);
        }
    }
#pragma unroll
    for (int t = 0; t < 4; ++t) {
        float2 b = cmul(e[t + 4], v1);
        if (t == 1)      b = make_float2(RSQ2 * (b.x - b.y), RSQ2 * (b.x + b.y));
        else if (t == 2) b = make_float2(-b.y, b.x);
        else if (t == 3) b = make_float2(-RSQ2 * (b.x + b.y), RSQ2 * (b.x - b.y));
        float2 a = e[t];
        e[t]     = make_float2(a.x + b.x, a.y + b.y);
        e[t + 4] = make_float2(a.x - b.x, a.y - b.y);
    }
#pragma unroll
    for (int t = 0; t < 8; ++t) buf[SW(i0 + t * s)] = e[t];
}

__global__ __launch_bounds__(NT, 4)   // (1024,4): R2-proven VGPR=64 allocator mode
void conv_fft_kernel(const float* __restrict__ x, float2* __restrict__ out) {
    __shared__ float2 smem[2 * TK];           // 128 KB static: two 8192-pt buffers
    float2* bufA = smem;
    float2* bufB = smem + TK;
    const int tid = threadIdx.x;
    const int b = blockIdx.x;
    const float4* __restrict__ xrow4 =
        reinterpret_cast<const float4*>(x + (size_t)b * TFULL);

    float2 acc[8];
#pragma unroll
    for (int c = 0; c < 8; ++c) acc[c] = make_float2(0.f, 0.f);

    for (int jp = 0; jp < 2; ++jp) {          // FFT pair: j = 2jp (A), 2jp+1 (B)
        // global float4 load fused with first DIF stage (h = 4096), both buffers
#pragma unroll
        for (int c4 = 0; c4 < 4; ++c4) {
            int u = c4 * NT + tid;
            float4 a  = xrow4[2 * u + jp];                 // (reA,imA,reB,imB) @ u
            float4 b2 = xrow4[2 * (u + HALF_TK) + jp];     // @ u+4096
            float2 w = g_W[u];
            bufA[SW(u)] = make_float2(a.x + b2.x, a.y + b2.y);
            bufA[SW(u + HALF_TK)] = cmul(make_float2(a.x - b2.x, a.y - b2.y), w);
            bufB[SW(u)] = make_float2(a.z + b2.z, a.w + b2.w);
            bufB[SW(u + HALF_TK)] = cmul(make_float2(a.z - b2.z, a.w - b2.w), w);
        }
        __syncthreads();
        fwd_pass<9>(bufA, tid); SCHED_FENCE(); fwd_pass<9>(bufB, tid);
        __syncthreads();
        // C6 -> C3 -> C0 communicate only within a wave: compiler fence only
        fwd_pass<6>(bufA, tid); SCHED_FENCE(); fwd_pass<6>(bufB, tid);
        WAVE_SYNC();
        fwd_pass<3>(bufA, tid); SCHED_FENCE(); fwd_pass<3>(bufB, tid);
        WAVE_SYNC();
        fwd_pass<0>(bufA, tid); SCHED_FENCE(); fwd_pass<0>(bufB, tid);
        __syncthreads();
        // accumulate at r = 8*tid + c: y_hat += Z*P + conj(Z[-t])*Q
        // A half, then (fenced) B half so Zt/Zm live ranges stay disjoint.
        {
            const float2* __restrict__ PA = g_P + (size_t)(2 * jp) * TK;
            const float2* __restrict__ QA = g_Q + (size_t)(2 * jp) * TK;
#pragma unroll
            for (int c = 0; c < 8; ++c) {
                int r = 8 * tid + c;
                unsigned t = br13((unsigned)r);
                unsigned tm = (TK - t) & (TK - 1);
                int r2 = (int)br13(tm);
                float2 Zt = bufA[SW(r)], Zm = bufA[SW(r2)];
                float2 Pv = PA[r], Qv = QA[r];
                acc[c].x += Zt.x * Pv.x - Zt.y * Pv.y + Zm.x * Qv.x + Zm.y * Qv.y;
                acc[c].y += Zt.x * Pv.y + Zt.y * Pv.x + Zm.x * Qv.y - Zm.y * Qv.x;
            }
        }
        SCHED_FENCE();
        {
            const float2* __restrict__ PB = g_P + (size_t)(2 * jp + 1) * TK;
            const float2* __restrict__ QB = g_Q + (size_t)(2 * jp + 1) * TK;
#pragma unroll
            for (int c = 0; c < 8; ++c) {
                int r = 8 * tid + c;
                unsigned t = br13((unsigned)r);
                unsigned tm = (TK - t) & (TK - 1);
                int r2 = (int)br13(tm);
                float2 Zt = bufB[SW(r)], Zm = bufB[SW(r2)];
                float2 Pv = PB[r], Qv = QB[r];
                acc[c].x += Zt.x * Pv.x - Zt.y * Pv.y + Zm.x * Qv.x + Zm.y * Qv.y;
                acc[c].y += Zt.x * Pv.y + Zt.y * Pv.x + Zm.x * Qv.y - Zm.y * Qv.x;
            }
        }
        __syncthreads();
    }

    // First inverse radix-8 pass (C=0, unit twiddles) in registers:
    // thread tid owns y_hat_br[8*tid .. 8*tid+8) == acc[0..8)  (validated R5)
    {
        float2 e[8];
#pragma unroll
        for (int t = 0; t < 8; t += 2) {
            float2 a = acc[t], bb = acc[t + 1];
            e[t]     = make_float2(a.x + bb.x, a.y + bb.y);
            e[t + 1] = make_float2(a.x - bb.x, a.y - bb.y);
        }
#pragma unroll
        for (int t0 = 0; t0 < 8; t0 += 4) {
            {
                float2 a = e[t0], bb = e[t0 + 2];
                e[t0]     = make_float2(a.x + bb.x, a.y + bb.y);
                e[t0 + 2] = make_float2(a.x - bb.x, a.y - bb.y);
            }
            {
                float2 a = e[t0 + 1], bb = e[t0 + 3];
                bb = make_float2(-bb.y, bb.x);
                e[t0 + 1] = make_float2(a.x + bb.x, a.y + bb.y);
                e[t0 + 3] = make_float2(a.x - bb.x, a.y - bb.y);
            }
        }
#pragma unroll
        for (int t = 0; t < 4; ++t) {
            float2 bb = e[t + 4];
            if (t == 1)      bb = make_float2(RSQ2 * (bb.x - bb.y), RSQ2 * (bb.x + bb.y));
            else if (t == 2) bb = make_float2(-bb.y, bb.x);
            else if (t == 3) bb = make_float2(-RSQ2 * (bb.x + bb.y), RSQ2 * (bb.x - bb.y));
            float2 a = e[t];
            e[t]     = make_float2(a.x + bb.x, a.y + bb.y);
            e[t + 4] = make_float2(a.x - bb.x, a.y - bb.y);
        }
#pragma unroll
        for (int t = 0; t < 8; ++t) bufA[SW(8 * tid + t)] = e[t];
    }
    WAVE_SYNC();
    // C0 -> C3 -> C6 same-wave; barrier before the cross-wave C9
    inv_pass<3>(bufA, tid);
    WAVE_SYNC();
    inv_pass<6>(bufA, tid);
    __syncthreads();
    inv_pass<9>(bufA, tid);
    __syncthreads();
    // final DIT stage (h = 4096) fused with global store
    float2* __restrict__ orow = out + (size_t)b * TK;
#pragma unroll
    for (int c4 = 0; c4 < 4; ++c4) {
        int u = c4 * NT + tid;
        float2 a = bufA[SW(u)];
        float2 w = g_W[u]; w.y = -w.y;
        float2 bb = cmul(bufA[SW(u + HALF_TK)], w);
        orow[u]           = make_float2(a.x + bb.x, a.y + bb.y);
        orow[u + HALF_TK] = make_float2(a.x - bb.x, a.y - bb.y);
    }
}

extern "C" void kernel_launch(void* const* d_in, const int* in_sizes, int n_in,
                              void* d_out, int out_size, void* d_ws, size_t ws_size,
                              hipStream_t stream) {
    const float* x    = (const float*)d_in[0];
    const float* filt = (const float*)d_in[1];
    const int T = in_sizes[1];          // 65536
    const int B = in_sizes[0] / T;      // 256 rows
    (void)n_in; (void)d_ws; (void)ws_size; (void)out_size; (void)T;

    build_twiddle_kernel<<<HALF_TK / 256, 256, 0, stream>>>();
    build_pq_kernel<<<TK / 256, 256, 0, stream>>>(filt);
    conv_fft_kernel<<<B, NT, 0, stream>>>(x, (float2*)d_out);
}